// Round 4
// baseline (195.910 us; speedup 1.0000x reference)
//
#include <hip/hip_runtime.h>
#include <hip/hip_bf16.h>

// AttentionBlock: GroupNorm(8) -> QKV 1x1 -> softmax attention (hw=1024, c=256) -> proj + residual
// B=32, C=256, H=W=32. Inputs fp32, OUTPUT fp32. Internals bf16 MFMA, fp32 accum.
// R13:
//  - attn: double-buffered Kt/Vs (LDS 87.5 -> 154 KB, still 1 block/CU so occupancy unchanged).
//    Barriers 3/iter -> 2/iter: staging ds_writes of tile i+1 go into the idle buffer
//    CONCURRENTLY with QK MFMAs on tile i; the P-exchange barrier publishes them.
//    Hazards: stage(it+1)->buf[cur] is after bar_end(it) which follows PV(it) reads of Vs[cur];
//    P-write(it+1) after bar_end(it) follows P-read(it). All conflicts barrier-separated.
//  - gn/qkv/proj unchanged from R12 (clean A/B on attn).
// ws: xnT 16MB | qtr 16MB | ktr 16MB | v 16MB | aoT 16MB | wbf 512KB.

typedef __bf16 bf16x8 __attribute__((ext_vector_type(8)));
typedef __bf16 bf16x4 __attribute__((ext_vector_type(4)));
typedef __bf16 bf16x2 __attribute__((ext_vector_type(2)));
typedef float f32x4 __attribute__((ext_vector_type(4)));
typedef float f32x16 __attribute__((ext_vector_type(16)));

#define MFMA16(a, b, c) __builtin_amdgcn_mfma_f32_16x16x32_bf16(a, b, c, 0, 0, 0)
#define MFMA32(a, b, c) __builtin_amdgcn_mfma_f32_32x32x16_bf16(a, b, c, 0, 0, 0)

// ---------------- K1: GroupNorm fp32 [b][c][s] -> bf16 xnT [b][s][c]  (+ fused weight convert) ----------------
__global__ __launch_bounds__(512) void gn_kernel(const float* __restrict__ x,
                                                 const float* __restrict__ gw,
                                                 const float* __restrict__ gb,
                                                 __bf16* __restrict__ xnT,
                                                 const float* __restrict__ wqkv,
                                                 const float* __restrict__ wout,
                                                 __bf16* __restrict__ wbf) {
    __shared__ float red[16];
    __shared__ float stats[2];
    __shared__ __bf16 Lds[512][40];
    const int b = blockIdx.x >> 3, g = blockIdx.x & 7;
    const size_t base = ((size_t)b * 256 + g * 32) * 1024;
    const float* xp = x + base;
    const int t = threadIdx.x;                // 0..511

    // fused wconv: 256 blocks * 512 thr * 2 floats = 262144 (wqkv 196608 | wout 65536)
    {
        int widx = (blockIdx.x * 512 + t) * 2;
        const float* wsrc = (widx < 196608) ? (wqkv + widx) : (wout + (widx - 196608));
        float2 wv = *(const float2*)wsrc;
        bf16x2 wo;
        wo[0] = (__bf16)wv.x; wo[1] = (__bf16)wv.y;
        *(bf16x2*)&wbf[widx] = wo;
    }

    float s = 0.f, s2 = 0.f;
    #pragma unroll
    for (int i = 0; i < 8; i++) {
        int j = i * 512 + t;                  // 8-elem chunk index
        float4 v0 = *(const float4*)(xp + (size_t)j * 8);
        float4 v1 = *(const float4*)(xp + (size_t)j * 8 + 4);
        s  += v0.x + v0.y + v0.z + v0.w + v1.x + v1.y + v1.z + v1.w;
        s2 += v0.x*v0.x + v0.y*v0.y + v0.z*v0.z + v0.w*v0.w
            + v1.x*v1.x + v1.y*v1.y + v1.z*v1.z + v1.w*v1.w;
    }
    #pragma unroll
    for (int o = 32; o > 0; o >>= 1) { s += __shfl_down(s, o, 64); s2 += __shfl_down(s2, o, 64); }
    const int wv = t >> 6;
    if ((t & 63) == 0) { red[wv * 2] = s; red[wv * 2 + 1] = s2; }
    __syncthreads();
    if (t == 0) {
        float ts = 0.f, ts2 = 0.f;
        for (int w = 0; w < 8; w++) { ts += red[w * 2]; ts2 += red[w * 2 + 1]; }
        float mean = ts / 32768.f;
        float var = ts2 / 32768.f - mean * mean;
        stats[0] = mean; stats[1] = rsqrtf(var + 1e-5f);
    }
    __syncthreads();
    const float mean = stats[0], inv = stats[1];

    const int c = t >> 4;                 // 0..31 channel within group
    const int so = (t & 15) * 2;          // s sub-offset (pairs)
    const float ga = gw[g * 32 + c], be = gb[g * 32 + c];

    for (int chunk = 0; chunk < 1024; chunk += 512) {
        #pragma unroll
        for (int i = 0; i < 16; i++) {
            int sl = so + i * 32;
            float2 v = *(const float2*)(xp + (size_t)c * 1024 + chunk + sl);
            Lds[sl][c]     = (__bf16)((v.x - mean) * inv * ga + be);
            Lds[sl + 1][c] = (__bf16)((v.y - mean) * inv * ga + be);
        }
        __syncthreads();
        {
            int sl = t;                   // one s-row per thread
            #pragma unroll
            for (int u = 0; u < 4; u++) {
                bf16x8 vv = *(const bf16x8*)&Lds[sl][u * 8];
                *(bf16x8*)&xnT[((size_t)b * 1024 + chunk + sl) * 256 + g * 32 + u * 8] = vv;
            }
        }
        __syncthreads();
    }
}

// ---------------- shared 128x128 GEMM body, BK=64, register-prefetch pipeline ----------------
#define GEMM64_BODY(ArowBase_, BrowBase_)                                               \
    f32x4 acc[4][4] = {};                                                               \
    const int r_ = t >> 1, kc_ = (t & 1) * 32;                                          \
    bf16x8 pa[4], pb[4];                                                                \
    _Pragma("unroll")                                                                   \
    for (int u = 0; u < 4; u++) {                                                       \
        pa[u] = *(const bf16x8*)&(ArowBase_)[(size_t)r_ * 256 + kc_ + u * 8];           \
        pb[u] = *(const bf16x8*)&(BrowBase_)[(size_t)r_ * 256 + kc_ + u * 8];           \
    }                                                                                   \
    for (int kk = 0; kk < 256; kk += 64) {                                              \
        _Pragma("unroll")                                                               \
        for (int u = 0; u < 4; u++) {                                                   \
            *(bf16x8*)&As[r_][kc_ + u * 8] = pa[u];                                     \
            *(bf16x8*)&Bs[r_][kc_ + u * 8] = pb[u];                                     \
        }                                                                               \
        __syncthreads();                                                                \
        if (kk < 192) {                                                                 \
            _Pragma("unroll")                                                           \
            for (int u = 0; u < 4; u++) {                                               \
                pa[u] = *(const bf16x8*)&(ArowBase_)[(size_t)r_ * 256 + kk + 64 + kc_ + u * 8]; \
                pb[u] = *(const bf16x8*)&(BrowBase_)[(size_t)r_ * 256 + kk + 64 + kc_ + u * 8]; \
            }                                                                           \
        }                                                                               \
        _Pragma("unroll")                                                               \
        for (int kh = 0; kh < 2; kh++) {                                                \
            bf16x8 af[4], bfv[4];                                                       \
            _Pragma("unroll")                                                           \
            for (int im = 0; im < 4; im++)                                              \
                af[im] = *(const bf16x8*)&As[wm + im * 16 + l16][kh * 32 + quad * 8];   \
            _Pragma("unroll")                                                           \
            for (int in = 0; in < 4; in++)                                              \
                bfv[in] = *(const bf16x8*)&Bs[wn + in * 16 + l16][kh * 32 + quad * 8];  \
            _Pragma("unroll")                                                           \
            for (int im = 0; im < 4; im++)                                              \
                _Pragma("unroll")                                                       \
                for (int in = 0; in < 4; in++)                                          \
                    acc[im][in] = MFMA16(af[im], bfv[in], acc[im][in]);                 \
        }                                                                               \
        __syncthreads();                                                                \
    }

// ---------------- K2: QKV GEMM, 128x128 tiles, bf16 weights, LDS-staged epilogues ----------------
__global__ __launch_bounds__(256) void qkv_gemm(const __bf16* __restrict__ wbf,
                                                const float* __restrict__ bias,
                                                const __bf16* __restrict__ xnT,
                                                __bf16* __restrict__ qtr,
                                                __bf16* __restrict__ ktr,
                                                __bf16* __restrict__ vbuf) {
    __shared__ union {
        struct { __bf16 A[128][72]; __bf16 B[128][72]; } g;   // 36864 B main loop
        __bf16 ct[128][136];                                  // 34816 B epilogue
    } sm;
    const int b = blockIdx.z;
    const int n0 = blockIdx.x * 128, m0 = blockIdx.y * 128;
    const int t = threadIdx.x;
    const int wave = t >> 6, lane = t & 63, quad = lane >> 4, l16 = lane & 15;
    const int wm = (wave & 1) * 64, wn = (wave >> 1) * 64;
    const __bf16* arow = wbf + (size_t)m0 * 256;
    const __bf16* brow = xnT + ((size_t)b * 1024 + n0) * 256;
    auto As = sm.g.A;
    auto Bs = sm.g.B;

    GEMM64_BODY(arow, brow)

    if (m0 < 512) {
        // q/k path: transpose C-tile into LDS [s][c], then coalesced bf16x8 stores.
        #pragma unroll
        for (int im = 0; im < 4; im++) {
            #pragma unroll
            for (int in = 0; in < 4; in++) {
                int ob = m0 + wm + im * 16 + quad * 4;
                bf16x4 ov;
                #pragma unroll
                for (int r = 0; r < 4; r++) ov[r] = (__bf16)(acc[im][in][r] + bias[ob + r]);
                *(bf16x4*)&sm.ct[wn + in * 16 + l16][wm + im * 16 + quad * 4] = ov;
            }
        }
        __syncthreads();
        {
            const int rbase = t >> 2, cf = t & 3;
            #pragma unroll
            for (int rr = 0; rr < 2; rr++) {
                int row = rbase + rr * 64;
                int sg = n0 + row;
                __bf16* dst = (m0 < 256) ? &qtr[((size_t)b * 1024 + sg) * 256 + m0]
                                         : &ktr[((size_t)b * 1024 + sg) * 256 + (m0 - 256)];
                #pragma unroll
                for (int u = 0; u < 4; u++) {
                    int colb = cf * 8 + u * 32;
                    *(bf16x8*)&dst[colb] = *(const bf16x8*)&sm.ct[row][colb];
                }
            }
        }
    } else {
        // v path: stage C-tile into LDS as [c][t], then fully-coalesced b128 stores to vbuf [b][c][t].
        #pragma unroll
        for (int im = 0; im < 4; im++) {
            #pragma unroll
            for (int in = 0; in < 4; in++) {
                int cl = wm + im * 16 + quad * 4;
                int tl = wn + in * 16 + l16;
                #pragma unroll
                for (int r = 0; r < 4; r++)
                    sm.ct[cl + r][tl] = (__bf16)(acc[im][in][r] + bias[m0 + cl + r]);
            }
        }
        __syncthreads();
        {
            const int row = t >> 1, tc = (t & 1) * 64;   // c_local row, t-chunk base
            const int cglob = m0 - 512 + row;
            __bf16* dst = &vbuf[((size_t)b * 256 + cglob) * 1024 + n0 + tc];
            #pragma unroll
            for (int u = 0; u < 8; u++)
                *(bf16x8*)&dst[u * 8] = *(const bf16x8*)&sm.ct[row][tc + u * 8];
        }
    }
}

// ---------------- K3: fused flash attention (R13: double-buffered K/V, 2 barriers/iter) ----------------
__global__ __launch_bounds__(512, 2) void attn_kernel(const __bf16* __restrict__ qtr,
                                                      const __bf16* __restrict__ ktr,
                                                      const __bf16* __restrict__ vbuf,
                                                      __bf16* __restrict__ aoT) {
    __shared__ __bf16 Kt[2][2][32][260];  // [buf][t-half][t_local][c]
    __shared__ __bf16 Vs[2][2][256][36];  // [buf][t-half][c][slot] (slot = permuted t within 16-chunks)
    __shared__ bf16x8 Pl[4][2][2][64];    // [pair][th][chunk][lane] P-fragments for partner wave
    __shared__ float Lred[4][2][32];      // [pair][th][s_local]
    const int b = blockIdx.x;
    const int tid = threadIdx.x;
    const int wave = tid >> 6, lane = tid & 63, half = lane >> 5, l31 = lane & 31;
    const int pair = wave & 3, th = wave >> 2;
    const int s0 = blockIdx.y * 128 + pair * 32;
    const float kscale = 0.09016844f;   // (1/16) * log2(e); p = exp2(s * kscale)

    // Q fragments (B-operand of swapped QK: lane = s-col, elems = c)
    bf16x8 aq[16];
    #pragma unroll
    for (int ks = 0; ks < 16; ks++)
        aq[ks] = *(const bf16x8*)&qtr[((size_t)b * 1024 + s0 + l31) * 256 + ks * 16 + half * 8];

    const int k_row = tid >> 3;
    const int k_cb  = (tid & 7) * 8;
    const int v_c   = tid >> 1;
    const int v_th  = tid & 1;
    const size_t kbase = (size_t)b * 1024 * 256;
    const size_t vbase = (size_t)b * 256 * 1024;

    float l_acc = 0.f;
    f32x16 o_acc[4] = {};
    bf16x8 kpre[4], vpre[4];

#define LOAD_KV(T_)                                                                           \
    _Pragma("unroll")                                                                         \
    for (int u = 0; u < 4; u++) {                                                             \
        kpre[u] = *(const bf16x8*)&ktr[kbase + (size_t)((T_) + k_row) * 256 + k_cb + u * 64]; \
        vpre[u] = *(const bf16x8*)&vbuf[vbase + (size_t)v_c * 1024 + (T_) + v_th * 32 + u * 8]; \
    }

#define STAGE_KV(bb_)                                                                         \
    _Pragma("unroll")                                                                         \
    for (int u = 0; u < 4; u++)                                                               \
        *(bf16x8*)&Kt[bb_][k_row >> 5][k_row & 31][k_cb + u * 64] = kpre[u];                  \
    _Pragma("unroll")                                                                         \
    for (int u = 0; u < 4; u++) {                                                             \
        const bf16x4* hv = (const bf16x4*)&vpre[u];                                           \
        const int sbase = (u >> 1) * 16 + (u & 1) * 4;                                        \
        *(bf16x4*)&Vs[bb_][v_th][v_c][sbase]     = hv[0];                                     \
        *(bf16x4*)&Vs[bb_][v_th][v_c][sbase + 8] = hv[1];                                     \
    }

    // prologue: tile 0 -> buf 0; prefetch tile 1 into regs; publish
    LOAD_KV(0)
    STAGE_KV(0)
    LOAD_KV(64)
    __syncthreads();

    for (int it = 0; it < 16; it++) {
        const int cur = it & 1;
        // stage tile it+1 into the idle buffer — overlaps with QK MFMAs below
        if (it < 15) { STAGE_KV(cur ^ 1) }
        // prefetch tile it+2 — flies under QK + softmax + PV
        if (it < 14) { LOAD_KV((it + 2) * 64) }

        // swapped QK^T: A = K (lane = t-row), B = Q (lane = s-col) -> C: regs = t, lane = s
        f32x16 sc_a = {}, sc_b = {};
        __builtin_amdgcn_s_setprio(1);
        #pragma unroll
        for (int ks = 0; ks < 8; ks++) {
            bf16x8 bk0 = *(const bf16x8*)&Kt[cur][th][l31][ks * 16 + half * 8];
            bf16x8 bk1 = *(const bf16x8*)&Kt[cur][th][l31][(ks + 8) * 16 + half * 8];
            sc_a = MFMA32(bk0, aq[ks], sc_a);
            sc_b = MFMA32(bk1, aq[ks + 8], sc_b);
        }
        __builtin_amdgcn_s_setprio(0);

        // softmax partial + P fragments (lane = s, regs = t -> direct PV A-operand)
        bf16x8 pf0, pf1;
        #pragma unroll
        for (int r = 0; r < 8; r++) {
            float p = exp2f((sc_a[r] + sc_b[r]) * kscale);
            l_acc += p;
            pf0[r] = (__bf16)p;
        }
        #pragma unroll
        for (int r = 8; r < 16; r++) {
            float p = exp2f((sc_a[r] + sc_b[r]) * kscale);
            l_acc += p;
            pf1[r - 8] = (__bf16)p;
        }
        Pl[pair][th][0][lane] = pf0;
        Pl[pair][th][1][lane] = pf1;
        __syncthreads();                      // P exchange + publish staged buf
        bf16x8 pp0 = Pl[pair][1 - th][0][lane];
        bf16x8 pp1 = Pl[pair][1 - th][1][lane];

        bf16x8 ap[4];
        if (th == 0) { ap[0] = pf0; ap[1] = pf1; ap[2] = pp0; ap[3] = pp1; }
        else         { ap[0] = pp0; ap[1] = pp1; ap[2] = pf0; ap[3] = pf1; }

        __builtin_amdgcn_s_setprio(1);
        #pragma unroll
        for (int n = 0; n < 4; n++) {
            int c = th * 128 + n * 32 + l31;
            #pragma unroll
            for (int kc = 0; kc < 4; kc++) {
                bf16x8 bv = *(const bf16x8*)&Vs[cur][kc >> 1][c][(kc & 1) * 16 + half * 8];
                o_acc[n] = MFMA32(ap[kc], bv, o_acc[n]);
            }
        }
        __builtin_amdgcn_s_setprio(0);
        __syncthreads();                      // protects next iter's stage into buf[cur] & P overwrite
    }
#undef LOAD_KV
#undef STAGE_KV

    // l reduction: combine lane-halves (same s), then th-pairs via LDS
    l_acc += __shfl_xor(l_acc, 32, 64);
    if (lane < 32) Lred[pair][th][l31] = l_acc;
    __syncthreads();
    #pragma unroll
    for (int r = 0; r < 16; r++) {
        int row = (r & 3) + 8 * (r >> 2) + 4 * half;
        float rinv = 1.0f / (Lred[pair][0][row] + Lred[pair][1][row]);
        #pragma unroll
        for (int n = 0; n < 4; n++) {
            int c = th * 128 + n * 32 + l31;
            aoT[((size_t)b * 1024 + s0 + row) * 256 + c] = (__bf16)(o_acc[n][r] * rinv);
        }
    }
}

// ---------------- K4: proj GEMM, 128x128 tiles, LDS-staged float4 epilogue ----------------
__global__ __launch_bounds__(256) void proj_gemm(const __bf16* __restrict__ wbf_out,
                                                 const float* __restrict__ bias,
                                                 const __bf16* __restrict__ aoT,
                                                 const float* __restrict__ resid,
                                                 float* __restrict__ Out) {
    __shared__ union {
        struct { __bf16 A[128][72]; __bf16 B[128][72]; } g;   // 36864 B main loop
        float cf[64][132];                                    // 33792 B epilogue (m-half)
    } sm;
    const int b = blockIdx.z;
    const int n0 = blockIdx.x * 128, m0 = blockIdx.y * 128;
    const int t = threadIdx.x;
    const int wave = t >> 6, lane = t & 63, quad = lane >> 4, l16 = lane & 15;
    const int wm = (wave & 1) * 64, wn = (wave >> 1) * 64;
    const __bf16* arow = wbf_out + (size_t)m0 * 256;
    const __bf16* brow = aoT + ((size_t)b * 1024 + n0) * 256;
    auto As = sm.g.A;
    auto Bs = sm.g.B;

    GEMM64_BODY(arow, brow)

    for (int h = 0; h < 2; h++) {
        if ((wave & 1) == h) {
            #pragma unroll
            for (int im = 0; im < 4; im++)
                #pragma unroll
                for (int in = 0; in < 4; in++)
                    #pragma unroll
                    for (int r = 0; r < 4; r++)
                        sm.cf[im * 16 + quad * 4 + r][wn + in * 16 + l16] = acc[im][in][r];
        }
        __syncthreads();
        {
            const int rloc = t >> 2, cq = (t & 3) * 4;
            const int o = m0 + h * 64 + rloc;
            const float bo = bias[o];
            const float* rrow = &resid[((size_t)b * 256 + o) * 1024 + n0];
            float* orow = &Out[((size_t)b * 256 + o) * 1024 + n0];
            #pragma unroll
            for (int u = 0; u < 8; u++) {
                int col = cq + u * 16;
                f32x4 cv = *(const f32x4*)&sm.cf[rloc][col];
                float4 rv = *(const float4*)&rrow[col];
                float4 ov;
                ov.x = cv[0] + bo + rv.x;
                ov.y = cv[1] + bo + rv.y;
                ov.z = cv[2] + bo + rv.z;
                ov.w = cv[3] + bo + rv.w;
                *(float4*)&orow[col] = ov;
            }
        }
        __syncthreads();
    }
}

extern "C" void kernel_launch(void* const* d_in, const int* in_sizes, int n_in,
                              void* d_out, int out_size, void* d_ws, size_t ws_size,
                              hipStream_t stream) {
    const float* x    = (const float*)d_in[0];
    const float* gw   = (const float*)d_in[1];
    const float* gb   = (const float*)d_in[2];
    const float* wqkv = (const float*)d_in[3];
    const float* bqkv = (const float*)d_in[4];
    const float* wout = (const float*)d_in[5];
    const float* bout = (const float*)d_in[6];
    float* out = (float*)d_out;

    const size_t T16 = (size_t)32 * 1024 * 256;
    __bf16* xnT  = (__bf16*)d_ws;        // [b][s][c]
    __bf16* qtr  = xnT + T16;            // [b][s][c]
    __bf16* ktr  = qtr + T16;            // [b][t][c]
    __bf16* vbuf = ktr + T16;            // [b][c][t]
    __bf16* aoT  = vbuf + T16;           // [b][s][c]
    __bf16* wbf  = aoT + T16;            // wqkv_bf16 (196608) | wout_bf16 (65536)

    gn_kernel<<<dim3(256), 512, 0, stream>>>(x, gw, gb, xnT, wqkv, wout, wbf);
    qkv_gemm<<<dim3(8, 6, 32), 256, 0, stream>>>(wbf, bqkv, xnT, qtr, ktr, vbuf);
    attn_kernel<<<dim3(32, 8), 512, 0, stream>>>(qtr, ktr, vbuf, aoT);
    proj_gemm<<<dim3(8, 2, 32), 256, 0, stream>>>(wbf + 196608, bout, aoT, x, out);
}

// Round 5
// 190.735 us; speedup vs baseline: 1.0271x; 1.0271x over previous
//
#include <hip/hip_runtime.h>
#include <hip/hip_bf16.h>

// AttentionBlock: GroupNorm(8) -> QKV 1x1 -> softmax attention (hw=1024, c=256) -> proj + residual
// B=32, C=256, H=W=32. Inputs fp32, OUTPUT fp32. Internals bf16 MFMA, fp32 accum.
// R14:
//  - attn: reverted to R12 structure (55.4us proven; R13 dbuf regressed to 58 -> barrier wasn't
//    the limiter, __syncthreads drains vmcnt either way).
//  - qkv/proj GEMM body rewritten m97-style: global_load_lds width=16 staging (DMA direct to LDS,
//    no reg round-trip), LINEAR LDS [128][64] with T2 XOR chunk-swizzle (chunk ^= row&7) applied
//    both-sides (inverse-swizzled global SOURCE + swizzled frag READ) -> conflict-free b128 reads.
//    LDS 36.9->32KB main loop; ~4 blocks/CU co-resident hides the vmcnt(0) barrier drain.
// ws: xnT 16MB | qtr 16MB | ktr 16MB | v 16MB | aoT 16MB | wbf 512KB.

typedef __bf16 bf16x8 __attribute__((ext_vector_type(8)));
typedef __bf16 bf16x4 __attribute__((ext_vector_type(4)));
typedef __bf16 bf16x2 __attribute__((ext_vector_type(2)));
typedef float f32x4 __attribute__((ext_vector_type(4)));
typedef float f32x16 __attribute__((ext_vector_type(16)));

#define MFMA16(a, b, c) __builtin_amdgcn_mfma_f32_16x16x32_bf16(a, b, c, 0, 0, 0)
#define MFMA32(a, b, c) __builtin_amdgcn_mfma_f32_32x32x16_bf16(a, b, c, 0, 0, 0)

#define GLD16(gsrc_, ldst_)                                                                  \
    __builtin_amdgcn_global_load_lds((const __attribute__((address_space(1))) void*)(gsrc_), \
                                     (__attribute__((address_space(3))) void*)(ldst_), 16, 0, 0)

// ---------------- K1: GroupNorm fp32 [b][c][s] -> bf16 xnT [b][s][c]  (+ fused weight convert) ----------------
__global__ __launch_bounds__(512) void gn_kernel(const float* __restrict__ x,
                                                 const float* __restrict__ gw,
                                                 const float* __restrict__ gb,
                                                 __bf16* __restrict__ xnT,
                                                 const float* __restrict__ wqkv,
                                                 const float* __restrict__ wout,
                                                 __bf16* __restrict__ wbf) {
    __shared__ float red[16];
    __shared__ float stats[2];
    __shared__ __bf16 Lds[512][40];
    const int b = blockIdx.x >> 3, g = blockIdx.x & 7;
    const size_t base = ((size_t)b * 256 + g * 32) * 1024;
    const float* xp = x + base;
    const int t = threadIdx.x;                // 0..511

    // fused wconv: 256 blocks * 512 thr * 2 floats = 262144 (wqkv 196608 | wout 65536)
    {
        int widx = (blockIdx.x * 512 + t) * 2;
        const float* wsrc = (widx < 196608) ? (wqkv + widx) : (wout + (widx - 196608));
        float2 wv = *(const float2*)wsrc;
        bf16x2 wo;
        wo[0] = (__bf16)wv.x; wo[1] = (__bf16)wv.y;
        *(bf16x2*)&wbf[widx] = wo;
    }

    float s = 0.f, s2 = 0.f;
    #pragma unroll
    for (int i = 0; i < 8; i++) {
        int j = i * 512 + t;                  // 8-elem chunk index
        float4 v0 = *(const float4*)(xp + (size_t)j * 8);
        float4 v1 = *(const float4*)(xp + (size_t)j * 8 + 4);
        s  += v0.x + v0.y + v0.z + v0.w + v1.x + v1.y + v1.z + v1.w;
        s2 += v0.x*v0.x + v0.y*v0.y + v0.z*v0.z + v0.w*v0.w
            + v1.x*v1.x + v1.y*v1.y + v1.z*v1.z + v1.w*v1.w;
    }
    #pragma unroll
    for (int o = 32; o > 0; o >>= 1) { s += __shfl_down(s, o, 64); s2 += __shfl_down(s2, o, 64); }
    const int wv = t >> 6;
    if ((t & 63) == 0) { red[wv * 2] = s; red[wv * 2 + 1] = s2; }
    __syncthreads();
    if (t == 0) {
        float ts = 0.f, ts2 = 0.f;
        for (int w = 0; w < 8; w++) { ts += red[w * 2]; ts2 += red[w * 2 + 1]; }
        float mean = ts / 32768.f;
        float var = ts2 / 32768.f - mean * mean;
        stats[0] = mean; stats[1] = rsqrtf(var + 1e-5f);
    }
    __syncthreads();
    const float mean = stats[0], inv = stats[1];

    const int c = t >> 4;                 // 0..31 channel within group
    const int so = (t & 15) * 2;          // s sub-offset (pairs)
    const float ga = gw[g * 32 + c], be = gb[g * 32 + c];

    for (int chunk = 0; chunk < 1024; chunk += 512) {
        #pragma unroll
        for (int i = 0; i < 16; i++) {
            int sl = so + i * 32;
            float2 v = *(const float2*)(xp + (size_t)c * 1024 + chunk + sl);
            Lds[sl][c]     = (__bf16)((v.x - mean) * inv * ga + be);
            Lds[sl + 1][c] = (__bf16)((v.y - mean) * inv * ga + be);
        }
        __syncthreads();
        {
            int sl = t;                   // one s-row per thread
            #pragma unroll
            for (int u = 0; u < 4; u++) {
                bf16x8 vv = *(const bf16x8*)&Lds[sl][u * 8];
                *(bf16x8*)&xnT[((size_t)b * 1024 + chunk + sl) * 256 + g * 32 + u * 8] = vv;
            }
        }
        __syncthreads();
    }
}

// ---------------- shared 128x128 GEMM body v2: global_load_lds + XOR-swizzled linear LDS ----------------
// A = Wbf rows m0.., B = src rows (b*1024+n0).., K=256 in 4 steps of 64.
// Staging: 16 chunks of 1KB per operand per k-step; wave w issues chunks w*4+i.
//   lane l -> LDS row r=ch*8+(l>>3), chunk-pos l&7; SOURCE col-chunk = (l&7)^(r&7)  (inverse swz).
// Frag read: chunk-pos = (kh*4+quad)^(row&7) -> 8 rows spread over 8 chunk banks (2-way, free).
#define GEMM64G_BODY(ArowBase_, BrowBase_)                                              \
    f32x4 acc[4][4] = {};                                                               \
    for (int kk = 0; kk < 256; kk += 64) {                                              \
        _Pragma("unroll")                                                               \
        for (int i = 0; i < 4; i++) {                                                   \
            const int ch = wave * 4 + i;                                                \
            const int r = ch * 8 + (lane >> 3);                                         \
            const int sw = ((lane & 7) ^ (r & 7)) * 8;                                  \
            GLD16((ArowBase_) + (size_t)r * 256 + kk + sw, (char*)&As[0][0] + ch * 1024); \
            GLD16((BrowBase_) + (size_t)r * 256 + kk + sw, (char*)&Bs[0][0] + ch * 1024); \
        }                                                                               \
        __syncthreads();                                                                \
        _Pragma("unroll")                                                               \
        for (int kh = 0; kh < 2; kh++) {                                                \
            bf16x8 af[4], bfv[4];                                                       \
            _Pragma("unroll")                                                           \
            for (int im = 0; im < 4; im++) {                                            \
                const int row = wm + im * 16 + l16;                                     \
                af[im] = *(const bf16x8*)&As[row][(((kh * 4 + quad) ^ (row & 7)) * 8)]; \
            }                                                                           \
            _Pragma("unroll")                                                           \
            for (int in = 0; in < 4; in++) {                                            \
                const int row = wn + in * 16 + l16;                                     \
                bfv[in] = *(const bf16x8*)&Bs[row][(((kh * 4 + quad) ^ (row & 7)) * 8)]; \
            }                                                                           \
            _Pragma("unroll")                                                           \
            for (int im = 0; im < 4; im++)                                              \
                _Pragma("unroll")                                                       \
                for (int in = 0; in < 4; in++)                                          \
                    acc[im][in] = MFMA16(af[im], bfv[in], acc[im][in]);                 \
        }                                                                               \
        __syncthreads();                                                                \
    }

// ---------------- K2: QKV GEMM, 128x128 tiles, bf16 weights, LDS-staged epilogues ----------------
__global__ __launch_bounds__(256) void qkv_gemm(const __bf16* __restrict__ wbf,
                                                const float* __restrict__ bias,
                                                const __bf16* __restrict__ xnT,
                                                __bf16* __restrict__ qtr,
                                                __bf16* __restrict__ ktr,
                                                __bf16* __restrict__ vbuf) {
    __shared__ union {
        struct { __bf16 A[128][64]; __bf16 B[128][64]; } g;   // 32768 B main loop (linear, swz)
        __bf16 ct[128][136];                                  // 34816 B epilogue
    } sm;
    const int b = blockIdx.z;
    const int n0 = blockIdx.x * 128, m0 = blockIdx.y * 128;
    const int t = threadIdx.x;
    const int wave = t >> 6, lane = t & 63, quad = lane >> 4, l16 = lane & 15;
    const int wm = (wave & 1) * 64, wn = (wave >> 1) * 64;
    const __bf16* arow = wbf + (size_t)m0 * 256;
    const __bf16* brow = xnT + ((size_t)b * 1024 + n0) * 256;
    auto As = sm.g.A;
    auto Bs = sm.g.B;

    GEMM64G_BODY(arow, brow)

    if (m0 < 512) {
        // q/k path: transpose C-tile into LDS [s][c], then coalesced bf16x8 stores.
        #pragma unroll
        for (int im = 0; im < 4; im++) {
            #pragma unroll
            for (int in = 0; in < 4; in++) {
                int ob = m0 + wm + im * 16 + quad * 4;
                bf16x4 ov;
                #pragma unroll
                for (int r = 0; r < 4; r++) ov[r] = (__bf16)(acc[im][in][r] + bias[ob + r]);
                *(bf16x4*)&sm.ct[wn + in * 16 + l16][wm + im * 16 + quad * 4] = ov;
            }
        }
        __syncthreads();
        {
            const int rbase = t >> 2, cf = t & 3;
            #pragma unroll
            for (int rr = 0; rr < 2; rr++) {
                int row = rbase + rr * 64;
                int sg = n0 + row;
                __bf16* dst = (m0 < 256) ? &qtr[((size_t)b * 1024 + sg) * 256 + m0]
                                         : &ktr[((size_t)b * 1024 + sg) * 256 + (m0 - 256)];
                #pragma unroll
                for (int u = 0; u < 4; u++) {
                    int colb = cf * 8 + u * 32;
                    *(bf16x8*)&dst[colb] = *(const bf16x8*)&sm.ct[row][colb];
                }
            }
        }
    } else {
        // v path: stage C-tile into LDS as [c][t], then fully-coalesced b128 stores to vbuf [b][c][t].
        #pragma unroll
        for (int im = 0; im < 4; im++) {
            #pragma unroll
            for (int in = 0; in < 4; in++) {
                int cl = wm + im * 16 + quad * 4;
                int tl = wn + in * 16 + l16;
                #pragma unroll
                for (int r = 0; r < 4; r++)
                    sm.ct[cl + r][tl] = (__bf16)(acc[im][in][r] + bias[m0 + cl + r]);
            }
        }
        __syncthreads();
        {
            const int row = t >> 1, tc = (t & 1) * 64;   // c_local row, t-chunk base
            const int cglob = m0 - 512 + row;
            __bf16* dst = &vbuf[((size_t)b * 256 + cglob) * 1024 + n0 + tc];
            #pragma unroll
            for (int u = 0; u < 8; u++)
                *(bf16x8*)&dst[u * 8] = *(const bf16x8*)&sm.ct[row][tc + u * 8];
        }
    }
}

// ---------------- K3: fused flash attention (R12 structure: swapped QK^T, permuted-V, T14 prefetch) ----------------
__global__ __launch_bounds__(512, 2) void attn_kernel(const __bf16* __restrict__ qtr,
                                                      const __bf16* __restrict__ ktr,
                                                      const __bf16* __restrict__ vbuf,
                                                      __bf16* __restrict__ aoT) {
    __shared__ __bf16 Kt[2][32][260];     // [t-half][t_local][c]
    __shared__ __bf16 Vs[2][256][36];     // [t-half][c][slot]  (slot = permuted t within 16-chunks)
    __shared__ bf16x8 Pl[4][2][2][64];    // [pair][th][chunk][lane] P-fragments for partner wave
    __shared__ float Lred[4][2][32];      // [pair][th][s_local]
    const int b = blockIdx.x;
    const int tid = threadIdx.x;
    const int wave = tid >> 6, lane = tid & 63, half = lane >> 5, l31 = lane & 31;
    const int pair = wave & 3, th = wave >> 2;
    const int s0 = blockIdx.y * 128 + pair * 32;
    const float kscale = 0.09016844f;   // (1/16) * log2(e); p = exp2(s * kscale)

    // Q fragments (B-operand of swapped QK: lane = s-col, elems = c)
    bf16x8 aq[16];
    #pragma unroll
    for (int ks = 0; ks < 16; ks++)
        aq[ks] = *(const bf16x8*)&qtr[((size_t)b * 1024 + s0 + l31) * 256 + ks * 16 + half * 8];

    const int k_row = tid >> 3;
    const int k_cb  = (tid & 7) * 8;
    const int v_c   = tid >> 1;
    const int v_th  = tid & 1;
    const size_t kbase = (size_t)b * 1024 * 256;
    const size_t vbase = (size_t)b * 256 * 1024;

    float l_acc = 0.f;
    f32x16 o_acc[4] = {};

    // prologue: prefetch tile 0 into registers
    bf16x8 kpre[4], vpre[4];
    #pragma unroll
    for (int u = 0; u < 4; u++) {
        kpre[u] = *(const bf16x8*)&ktr[kbase + (size_t)k_row * 256 + k_cb + u * 64];
        vpre[u] = *(const bf16x8*)&vbuf[vbase + (size_t)v_c * 1024 + v_th * 32 + u * 8];
    }

    for (int it = 0; it < 16; it++) {
        // stage K (linear) and V (slot-permuted: within each 16-t chunk, t-groups [0-3,4-7,8-11,12-15]
        // land at slots [0-3,8-11,4-7,12-15] so p-register order matches MFMA k-slots)
        #pragma unroll
        for (int u = 0; u < 4; u++)
            *(bf16x8*)&Kt[k_row >> 5][k_row & 31][k_cb + u * 64] = kpre[u];
        #pragma unroll
        for (int u = 0; u < 4; u++) {
            const bf16x4* hv = (const bf16x4*)&vpre[u];
            const int sbase = (u >> 1) * 16 + (u & 1) * 4;   // 0,4,16,20
            *(bf16x4*)&Vs[v_th][v_c][sbase]     = hv[0];
            *(bf16x4*)&Vs[v_th][v_c][sbase + 8] = hv[1];
        }
        __syncthreads();
        // T14: issue next tile's global loads NOW — they fly under QK + softmax
        if (it < 15) {
            const int t1 = (it + 1) * 64;
            #pragma unroll
            for (int u = 0; u < 4; u++) {
                kpre[u] = *(const bf16x8*)&ktr[kbase + (size_t)(t1 + k_row) * 256 + k_cb + u * 64];
                vpre[u] = *(const bf16x8*)&vbuf[vbase + (size_t)v_c * 1024 + t1 + v_th * 32 + u * 8];
            }
        }

        // swapped QK^T: A = K (lane = t-row), B = Q (lane = s-col) -> C: regs = t, lane = s
        f32x16 sc_a = {}, sc_b = {};
        __builtin_amdgcn_s_setprio(1);
        #pragma unroll
        for (int ks = 0; ks < 8; ks++) {
            bf16x8 bk0 = *(const bf16x8*)&Kt[th][l31][ks * 16 + half * 8];
            bf16x8 bk1 = *(const bf16x8*)&Kt[th][l31][(ks + 8) * 16 + half * 8];
            sc_a = MFMA32(bk0, aq[ks], sc_a);
            sc_b = MFMA32(bk1, aq[ks + 8], sc_b);
        }
        __builtin_amdgcn_s_setprio(0);

        // softmax partial + P fragments (lane = s, regs = t -> direct PV A-operand)
        bf16x8 pf0, pf1;
        #pragma unroll
        for (int r = 0; r < 8; r++) {
            float p = exp2f((sc_a[r] + sc_b[r]) * kscale);
            l_acc += p;
            pf0[r] = (__bf16)p;
        }
        #pragma unroll
        for (int r = 8; r < 16; r++) {
            float p = exp2f((sc_a[r] + sc_b[r]) * kscale);
            l_acc += p;
            pf1[r - 8] = (__bf16)p;
        }
        Pl[pair][th][0][lane] = pf0;
        Pl[pair][th][1][lane] = pf1;
        __syncthreads();
        bf16x8 pp0 = Pl[pair][1 - th][0][lane];
        bf16x8 pp1 = Pl[pair][1 - th][1][lane];

        bf16x8 ap[4];
        if (th == 0) { ap[0] = pf0; ap[1] = pf1; ap[2] = pp0; ap[3] = pp1; }
        else         { ap[0] = pp0; ap[1] = pp1; ap[2] = pf0; ap[3] = pf1; }

        __builtin_amdgcn_s_setprio(1);
        #pragma unroll
        for (int n = 0; n < 4; n++) {
            int c = th * 128 + n * 32 + l31;
            #pragma unroll
            for (int kc = 0; kc < 4; kc++) {
                bf16x8 bv = *(const bf16x8*)&Vs[kc >> 1][c][(kc & 1) * 16 + half * 8];
                o_acc[n] = MFMA32(ap[kc], bv, o_acc[n]);
            }
        }
        __builtin_amdgcn_s_setprio(0);
        __syncthreads();
    }

    // l reduction: combine lane-halves (same s), then th-pairs via LDS
    l_acc += __shfl_xor(l_acc, 32, 64);
    if (lane < 32) Lred[pair][th][l31] = l_acc;
    __syncthreads();
    #pragma unroll
    for (int r = 0; r < 16; r++) {
        int row = (r & 3) + 8 * (r >> 2) + 4 * half;
        float rinv = 1.0f / (Lred[pair][0][row] + Lred[pair][1][row]);
        #pragma unroll
        for (int n = 0; n < 4; n++) {
            int c = th * 128 + n * 32 + l31;
            aoT[((size_t)b * 1024 + s0 + row) * 256 + c] = (__bf16)(o_acc[n][r] * rinv);
        }
    }
}

// ---------------- K4: proj GEMM, 128x128 tiles, LDS-staged float4 epilogue ----------------
__global__ __launch_bounds__(256) void proj_gemm(const __bf16* __restrict__ wbf_out,
                                                 const float* __restrict__ bias,
                                                 const __bf16* __restrict__ aoT,
                                                 const float* __restrict__ resid,
                                                 float* __restrict__ Out) {
    __shared__ union {
        struct { __bf16 A[128][64]; __bf16 B[128][64]; } g;   // 32768 B main loop (linear, swz)
        float cf[64][132];                                    // 33792 B epilogue (m-half)
    } sm;
    const int b = blockIdx.z;
    const int n0 = blockIdx.x * 128, m0 = blockIdx.y * 128;
    const int t = threadIdx.x;
    const int wave = t >> 6, lane = t & 63, quad = lane >> 4, l16 = lane & 15;
    const int wm = (wave & 1) * 64, wn = (wave >> 1) * 64;
    const __bf16* arow = wbf_out + (size_t)m0 * 256;
    const __bf16* brow = aoT + ((size_t)b * 1024 + n0) * 256;
    auto As = sm.g.A;
    auto Bs = sm.g.B;

    GEMM64G_BODY(arow, brow)

    for (int h = 0; h < 2; h++) {
        if ((wave & 1) == h) {
            #pragma unroll
            for (int im = 0; im < 4; im++)
                #pragma unroll
                for (int in = 0; in < 4; in++)
                    #pragma unroll
                    for (int r = 0; r < 4; r++)
                        sm.cf[im * 16 + quad * 4 + r][wn + in * 16 + l16] = acc[im][in][r];
        }
        __syncthreads();
        {
            const int rloc = t >> 2, cq = (t & 3) * 4;
            const int o = m0 + h * 64 + rloc;
            const float bo = bias[o];
            const float* rrow = &resid[((size_t)b * 256 + o) * 1024 + n0];
            float* orow = &Out[((size_t)b * 256 + o) * 1024 + n0];
            #pragma unroll
            for (int u = 0; u < 8; u++) {
                int col = cq + u * 16;
                f32x4 cv = *(const f32x4*)&sm.cf[rloc][col];
                float4 rv = *(const float4*)&rrow[col];
                float4 ov;
                ov.x = cv[0] + bo + rv.x;
                ov.y = cv[1] + bo + rv.y;
                ov.z = cv[2] + bo + rv.z;
                ov.w = cv[3] + bo + rv.w;
                *(float4*)&orow[col] = ov;
            }
        }
        __syncthreads();
    }
}

extern "C" void kernel_launch(void* const* d_in, const int* in_sizes, int n_in,
                              void* d_out, int out_size, void* d_ws, size_t ws_size,
                              hipStream_t stream) {
    const float* x    = (const float*)d_in[0];
    const float* gw   = (const float*)d_in[1];
    const float* gb   = (const float*)d_in[2];
    const float* wqkv = (const float*)d_in[3];
    const float* bqkv = (const float*)d_in[4];
    const float* wout = (const float*)d_in[5];
    const float* bout = (const float*)d_in[6];
    float* out = (float*)d_out;

    const size_t T16 = (size_t)32 * 1024 * 256;
    __bf16* xnT  = (__bf16*)d_ws;        // [b][s][c]
    __bf16* qtr  = xnT + T16;            // [b][s][c]
    __bf16* ktr  = qtr + T16;            // [b][t][c]
    __bf16* vbuf = ktr + T16;            // [b][c][t]
    __bf16* aoT  = vbuf + T16;           // [b][s][c]
    __bf16* wbf  = aoT + T16;            // wqkv_bf16 (196608) | wout_bf16 (65536)

    gn_kernel<<<dim3(256), 512, 0, stream>>>(x, gw, gb, xnT, wqkv, wout, wbf);
    qkv_gemm<<<dim3(8, 6, 32), 256, 0, stream>>>(wbf, bqkv, xnT, qtr, ktr, vbuf);
    attn_kernel<<<dim3(32, 8), 512, 0, stream>>>(qtr, ktr, vbuf, aoT);
    proj_gemm<<<dim3(8, 2, 32), 256, 0, stream>>>(wbf + 196608, bout, aoT, x, out);
}

// Round 6
// 186.425 us; speedup vs baseline: 1.0509x; 1.0231x over previous
//
#include <hip/hip_runtime.h>
#include <hip/hip_bf16.h>

// AttentionBlock: GroupNorm(8) -> QKV 1x1 -> softmax attention (hw=1024, c=256) -> proj + residual
// B=32, C=256, H=W=32. Inputs fp32, OUTPUT fp32. Internals bf16 MFMA, fp32 accum.
// R15:
//  - GN rebuilt as 2 kernels at 8 blocks/CU (was 1 block/CU latency-bound):
//    gn_stats: 2048 blocks, per-(group,part) partial sums written to ws (deterministic, no atomics).
//    gn_apply: 2048 blocks, reduces 8 partials (uniform s_loads), normalize + transpose via LDS.
//  - qkv/proj: XCD-chunked block swizzle (T1): the m-blocks sharing a B-panel are made
//    consecutive on the SAME XCD -> B-panel fetched ~once per XCD instead of 6x (qkv).
//  - attn: unchanged R12 structure (55.4us anchor). GEMM body = R14 global_load_lds + XOR swz.
// ws: xnT 16MB | qtr 16MB | ktr 16MB | v 16MB | aoT 16MB | wbf 512KB | gstats 16KB.

typedef __bf16 bf16x8 __attribute__((ext_vector_type(8)));
typedef __bf16 bf16x4 __attribute__((ext_vector_type(4)));
typedef float f32x4 __attribute__((ext_vector_type(4)));
typedef float f32x16 __attribute__((ext_vector_type(16)));

#define MFMA16(a, b, c) __builtin_amdgcn_mfma_f32_16x16x32_bf16(a, b, c, 0, 0, 0)
#define MFMA32(a, b, c) __builtin_amdgcn_mfma_f32_32x32x16_bf16(a, b, c, 0, 0, 0)

#define GLD16(gsrc_, ldst_)                                                                  \
    __builtin_amdgcn_global_load_lds((const __attribute__((address_space(1))) void*)(gsrc_), \
                                     (__attribute__((address_space(3))) void*)(ldst_), 16, 0, 0)

// ---------------- K0: GN partial stats (2048 blocks) + fused weight convert ----------------
__global__ __launch_bounds__(256) void gn_stats(const float* __restrict__ x,
                                                float* __restrict__ stats,
                                                const float* __restrict__ wqkv,
                                                const float* __restrict__ wout,
                                                __bf16* __restrict__ wbf) {
    const int bid = blockIdx.x, t = threadIdx.x;
    // fused wconv on first 128 blocks: 128*256*8 = 262144 (wqkv 196608 | wout 65536)
    if (bid < 128) {
        int idx = (bid * 256 + t) * 8;
        const float* src = (idx < 196608) ? (wqkv + idx) : (wout + (idx - 196608));
        float4 v0 = *(const float4*)src;
        float4 v1 = *(const float4*)(src + 4);
        bf16x8 o;
        o[0] = (__bf16)v0.x; o[1] = (__bf16)v0.y; o[2] = (__bf16)v0.z; o[3] = (__bf16)v0.w;
        o[4] = (__bf16)v1.x; o[5] = (__bf16)v1.y; o[6] = (__bf16)v1.z; o[7] = (__bf16)v1.w;
        *(bf16x8*)&wbf[idx] = o;
    }
    // partial sums: group bg (0..255), part (0..7), 4096 floats per block
    const int bg = bid >> 3, part = bid & 7;
    const float* xp = x + (size_t)bg * 32768 + part * 4096;
    float s = 0.f, s2 = 0.f;
    #pragma unroll
    for (int i = 0; i < 4; i++) {
        float4 v = *(const float4*)(xp + (i * 256 + t) * 4);
        s  += v.x + v.y + v.z + v.w;
        s2 += v.x*v.x + v.y*v.y + v.z*v.z + v.w*v.w;
    }
    #pragma unroll
    for (int o = 32; o > 0; o >>= 1) { s += __shfl_down(s, o, 64); s2 += __shfl_down(s2, o, 64); }
    __shared__ float red[8];
    const int wv = t >> 6;
    if ((t & 63) == 0) { red[wv * 2] = s; red[wv * 2 + 1] = s2; }
    __syncthreads();
    if (t == 0) {
        float ts  = red[0] + red[2] + red[4] + red[6];
        float ts2 = red[1] + red[3] + red[5] + red[7];
        stats[bg * 16 + part * 2]     = ts;
        stats[bg * 16 + part * 2 + 1] = ts2;
    }
}

// ---------------- K1: GN apply, fp32 [b][c][s] -> bf16 xnT [b][s][c], 2048 blocks ----------------
__global__ __launch_bounds__(512) void gn_apply(const float* __restrict__ x,
                                                const float* __restrict__ stats,
                                                const float* __restrict__ gw,
                                                const float* __restrict__ gb,
                                                __bf16* __restrict__ xnT) {
    const int bid = blockIdx.x;          // 0..2047
    const int bg = bid >> 3, part = bid & 7;
    const int b = bg >> 3, g = bg & 7;
    const int t = threadIdx.x;
    float ts = 0.f, ts2 = 0.f;
    #pragma unroll
    for (int p = 0; p < 8; p++) { ts += stats[bg * 16 + p * 2]; ts2 += stats[bg * 16 + p * 2 + 1]; }
    const float mean = ts / 32768.f;
    const float inv = rsqrtf(ts2 / 32768.f - mean * mean + 1e-5f);
    __shared__ __bf16 Lds[128][48];      // 48-stride: b128 reads 16B-aligned & conflict-free
    const int c = t >> 4, ss = (t & 15) * 8;
    const float ga = gw[g * 32 + c], be = gb[g * 32 + c];
    const float* xp = x + (((size_t)b * 256 + g * 32 + c) * 1024) + part * 128 + ss;
    float4 v0 = *(const float4*)xp;
    float4 v1 = *(const float4*)(xp + 4);
    float vv[8] = {v0.x, v0.y, v0.z, v0.w, v1.x, v1.y, v1.z, v1.w};
    #pragma unroll
    for (int i = 0; i < 8; i++) Lds[ss + i][c] = (__bf16)((vv[i] - mean) * inv * ga + be);
    __syncthreads();
    const int row = t >> 2, cb = (t & 3) * 8;
    bf16x8 ov = *(const bf16x8*)&Lds[row][cb];
    *(bf16x8*)&xnT[((size_t)b * 1024 + part * 128 + row) * 256 + g * 32 + cb] = ov;
}

// ---------------- shared 128x128 GEMM body: global_load_lds + XOR-swizzled linear LDS ----------------
#define GEMM64G_BODY(ArowBase_, BrowBase_)                                              \
    f32x4 acc[4][4] = {};                                                               \
    for (int kk = 0; kk < 256; kk += 64) {                                              \
        _Pragma("unroll")                                                               \
        for (int i = 0; i < 4; i++) {                                                   \
            const int ch = wave * 4 + i;                                                \
            const int r = ch * 8 + (lane >> 3);                                         \
            const int sw = ((lane & 7) ^ (r & 7)) * 8;                                  \
            GLD16((ArowBase_) + (size_t)r * 256 + kk + sw, (char*)&As[0][0] + ch * 1024); \
            GLD16((BrowBase_) + (size_t)r * 256 + kk + sw, (char*)&Bs[0][0] + ch * 1024); \
        }                                                                               \
        __syncthreads();                                                                \
        _Pragma("unroll")                                                               \
        for (int kh = 0; kh < 2; kh++) {                                                \
            bf16x8 af[4], bfv[4];                                                       \
            _Pragma("unroll")                                                           \
            for (int im = 0; im < 4; im++) {                                            \
                const int row = wm + im * 16 + l16;                                     \
                af[im] = *(const bf16x8*)&As[row][(((kh * 4 + quad) ^ (row & 7)) * 8)]; \
            }                                                                           \
            _Pragma("unroll")                                                           \
            for (int in = 0; in < 4; in++) {                                            \
                const int row = wn + in * 16 + l16;                                     \
                bfv[in] = *(const bf16x8*)&Bs[row][(((kh * 4 + quad) ^ (row & 7)) * 8)]; \
            }                                                                           \
            _Pragma("unroll")                                                           \
            for (int im = 0; im < 4; im++)                                              \
                _Pragma("unroll")                                                       \
                for (int in = 0; in < 4; in++)                                          \
                    acc[im][in] = MFMA16(af[im], bfv[in], acc[im][in]);                 \
        }                                                                               \
        __syncthreads();                                                                \
    }

// ---------------- K2: QKV GEMM, 128x128 tiles, XCD-chunked swizzle ----------------
__global__ __launch_bounds__(256) void qkv_gemm(const __bf16* __restrict__ wbf,
                                                const float* __restrict__ bias,
                                                const __bf16* __restrict__ xnT,
                                                __bf16* __restrict__ qtr,
                                                __bf16* __restrict__ ktr,
                                                __bf16* __restrict__ vbuf) {
    __shared__ union {
        struct { __bf16 A[128][64]; __bf16 B[128][64]; } g;   // 32768 B main loop (linear, swz)
        __bf16 ct[128][136];                                  // 34816 B epilogue
    } sm;
    // T1 swizzle: 1536 wgs, 192/XCD; 6 m-blocks of one (b,n0) B-panel consecutive on one XCD
    const int lin = blockIdx.x + ((blockIdx.y + blockIdx.z * 6) << 3);
    const int xcd = lin & 7, idx = lin >> 3;
    const int gwk = xcd * 192 + idx;
    const int mt = gwk % 6, panel = gwk / 6;
    const int b = panel >> 3;
    const int n0 = (panel & 7) * 128, m0 = mt * 128;
    const int t = threadIdx.x;
    const int wave = t >> 6, lane = t & 63, quad = lane >> 4, l16 = lane & 15;
    const int wm = (wave & 1) * 64, wn = (wave >> 1) * 64;
    const __bf16* arow = wbf + (size_t)m0 * 256;
    const __bf16* brow = xnT + ((size_t)b * 1024 + n0) * 256;
    auto As = sm.g.A;
    auto Bs = sm.g.B;

    GEMM64G_BODY(arow, brow)

    if (m0 < 512) {
        // q/k path: transpose C-tile into LDS [s][c], then coalesced bf16x8 stores.
        #pragma unroll
        for (int im = 0; im < 4; im++) {
            #pragma unroll
            for (int in = 0; in < 4; in++) {
                int ob = m0 + wm + im * 16 + quad * 4;
                bf16x4 ov;
                #pragma unroll
                for (int r = 0; r < 4; r++) ov[r] = (__bf16)(acc[im][in][r] + bias[ob + r]);
                *(bf16x4*)&sm.ct[wn + in * 16 + l16][wm + im * 16 + quad * 4] = ov;
            }
        }
        __syncthreads();
        {
            const int rbase = t >> 2, cf = t & 3;
            #pragma unroll
            for (int rr = 0; rr < 2; rr++) {
                int row = rbase + rr * 64;
                int sg = n0 + row;
                __bf16* dst = (m0 < 256) ? &qtr[((size_t)b * 1024 + sg) * 256 + m0]
                                         : &ktr[((size_t)b * 1024 + sg) * 256 + (m0 - 256)];
                #pragma unroll
                for (int u = 0; u < 4; u++) {
                    int colb = cf * 8 + u * 32;
                    *(bf16x8*)&dst[colb] = *(const bf16x8*)&sm.ct[row][colb];
                }
            }
        }
    } else {
        // v path: stage C-tile into LDS as [c][t], then fully-coalesced b128 stores to vbuf [b][c][t].
        #pragma unroll
        for (int im = 0; im < 4; im++) {
            #pragma unroll
            for (int in = 0; in < 4; in++) {
                int cl = wm + im * 16 + quad * 4;
                int tl = wn + in * 16 + l16;
                #pragma unroll
                for (int r = 0; r < 4; r++)
                    sm.ct[cl + r][tl] = (__bf16)(acc[im][in][r] + bias[m0 + cl + r]);
            }
        }
        __syncthreads();
        {
            const int row = t >> 1, tc = (t & 1) * 64;   // c_local row, t-chunk base
            const int cglob = m0 - 512 + row;
            __bf16* dst = &vbuf[((size_t)b * 256 + cglob) * 1024 + n0 + tc];
            #pragma unroll
            for (int u = 0; u < 8; u++)
                *(bf16x8*)&dst[u * 8] = *(const bf16x8*)&sm.ct[row][tc + u * 8];
        }
    }
}

// ---------------- K3: fused flash attention (R12 structure: swapped QK^T, permuted-V, T14 prefetch) ----------------
__global__ __launch_bounds__(512, 2) void attn_kernel(const __bf16* __restrict__ qtr,
                                                      const __bf16* __restrict__ ktr,
                                                      const __bf16* __restrict__ vbuf,
                                                      __bf16* __restrict__ aoT) {
    __shared__ __bf16 Kt[2][32][260];     // [t-half][t_local][c]
    __shared__ __bf16 Vs[2][256][36];     // [t-half][c][slot]  (slot = permuted t within 16-chunks)
    __shared__ bf16x8 Pl[4][2][2][64];    // [pair][th][chunk][lane] P-fragments for partner wave
    __shared__ float Lred[4][2][32];      // [pair][th][s_local]
    const int b = blockIdx.x;
    const int tid = threadIdx.x;
    const int wave = tid >> 6, lane = tid & 63, half = lane >> 5, l31 = lane & 31;
    const int pair = wave & 3, th = wave >> 2;
    const int s0 = blockIdx.y * 128 + pair * 32;
    const float kscale = 0.09016844f;   // (1/16) * log2(e); p = exp2(s * kscale)

    // Q fragments (B-operand of swapped QK: lane = s-col, elems = c)
    bf16x8 aq[16];
    #pragma unroll
    for (int ks = 0; ks < 16; ks++)
        aq[ks] = *(const bf16x8*)&qtr[((size_t)b * 1024 + s0 + l31) * 256 + ks * 16 + half * 8];

    const int k_row = tid >> 3;
    const int k_cb  = (tid & 7) * 8;
    const int v_c   = tid >> 1;
    const int v_th  = tid & 1;
    const size_t kbase = (size_t)b * 1024 * 256;
    const size_t vbase = (size_t)b * 256 * 1024;

    float l_acc = 0.f;
    f32x16 o_acc[4] = {};

    // prologue: prefetch tile 0 into registers
    bf16x8 kpre[4], vpre[4];
    #pragma unroll
    for (int u = 0; u < 4; u++) {
        kpre[u] = *(const bf16x8*)&ktr[kbase + (size_t)k_row * 256 + k_cb + u * 64];
        vpre[u] = *(const bf16x8*)&vbuf[vbase + (size_t)v_c * 1024 + v_th * 32 + u * 8];
    }

    for (int it = 0; it < 16; it++) {
        // stage K (linear) and V (slot-permuted: within each 16-t chunk, t-groups [0-3,4-7,8-11,12-15]
        // land at slots [0-3,8-11,4-7,12-15] so p-register order matches MFMA k-slots)
        #pragma unroll
        for (int u = 0; u < 4; u++)
            *(bf16x8*)&Kt[k_row >> 5][k_row & 31][k_cb + u * 64] = kpre[u];
        #pragma unroll
        for (int u = 0; u < 4; u++) {
            const bf16x4* hv = (const bf16x4*)&vpre[u];
            const int sbase = (u >> 1) * 16 + (u & 1) * 4;   // 0,4,16,20
            *(bf16x4*)&Vs[v_th][v_c][sbase]     = hv[0];
            *(bf16x4*)&Vs[v_th][v_c][sbase + 8] = hv[1];
        }
        __syncthreads();
        // T14: issue next tile's global loads NOW — they fly under QK + softmax
        if (it < 15) {
            const int t1 = (it + 1) * 64;
            #pragma unroll
            for (int u = 0; u < 4; u++) {
                kpre[u] = *(const bf16x8*)&ktr[kbase + (size_t)(t1 + k_row) * 256 + k_cb + u * 64];
                vpre[u] = *(const bf16x8*)&vbuf[vbase + (size_t)v_c * 1024 + t1 + v_th * 32 + u * 8];
            }
        }

        // swapped QK^T: A = K (lane = t-row), B = Q (lane = s-col) -> C: regs = t, lane = s
        f32x16 sc_a = {}, sc_b = {};
        __builtin_amdgcn_s_setprio(1);
        #pragma unroll
        for (int ks = 0; ks < 8; ks++) {
            bf16x8 bk0 = *(const bf16x8*)&Kt[th][l31][ks * 16 + half * 8];
            bf16x8 bk1 = *(const bf16x8*)&Kt[th][l31][(ks + 8) * 16 + half * 8];
            sc_a = MFMA32(bk0, aq[ks], sc_a);
            sc_b = MFMA32(bk1, aq[ks + 8], sc_b);
        }
        __builtin_amdgcn_s_setprio(0);

        // softmax partial + P fragments (lane = s, regs = t -> direct PV A-operand)
        bf16x8 pf0, pf1;
        #pragma unroll
        for (int r = 0; r < 8; r++) {
            float p = exp2f((sc_a[r] + sc_b[r]) * kscale);
            l_acc += p;
            pf0[r] = (__bf16)p;
        }
        #pragma unroll
        for (int r = 8; r < 16; r++) {
            float p = exp2f((sc_a[r] + sc_b[r]) * kscale);
            l_acc += p;
            pf1[r - 8] = (__bf16)p;
        }
        Pl[pair][th][0][lane] = pf0;
        Pl[pair][th][1][lane] = pf1;
        __syncthreads();
        bf16x8 pp0 = Pl[pair][1 - th][0][lane];
        bf16x8 pp1 = Pl[pair][1 - th][1][lane];

        bf16x8 ap[4];
        if (th == 0) { ap[0] = pf0; ap[1] = pf1; ap[2] = pp0; ap[3] = pp1; }
        else         { ap[0] = pp0; ap[1] = pp1; ap[2] = pf0; ap[3] = pf1; }

        __builtin_amdgcn_s_setprio(1);
        #pragma unroll
        for (int n = 0; n < 4; n++) {
            int c = th * 128 + n * 32 + l31;
            #pragma unroll
            for (int kc = 0; kc < 4; kc++) {
                bf16x8 bv = *(const bf16x8*)&Vs[kc >> 1][c][(kc & 1) * 16 + half * 8];
                o_acc[n] = MFMA32(ap[kc], bv, o_acc[n]);
            }
        }
        __builtin_amdgcn_s_setprio(0);
        __syncthreads();
    }

    // l reduction: combine lane-halves (same s), then th-pairs via LDS
    l_acc += __shfl_xor(l_acc, 32, 64);
    if (lane < 32) Lred[pair][th][l31] = l_acc;
    __syncthreads();
    #pragma unroll
    for (int r = 0; r < 16; r++) {
        int row = (r & 3) + 8 * (r >> 2) + 4 * half;
        float rinv = 1.0f / (Lred[pair][0][row] + Lred[pair][1][row]);
        #pragma unroll
        for (int n = 0; n < 4; n++) {
            int c = th * 128 + n * 32 + l31;
            aoT[((size_t)b * 1024 + s0 + row) * 256 + c] = (__bf16)(o_acc[n][r] * rinv);
        }
    }
}

// ---------------- K4: proj GEMM, 128x128 tiles, XCD-chunked swizzle ----------------
__global__ __launch_bounds__(256) void proj_gemm(const __bf16* __restrict__ wbf_out,
                                                 const float* __restrict__ bias,
                                                 const __bf16* __restrict__ aoT,
                                                 const float* __restrict__ resid,
                                                 float* __restrict__ Out) {
    __shared__ union {
        struct { __bf16 A[128][64]; __bf16 B[128][64]; } g;   // 32768 B main loop (linear, swz)
        float cf[64][132];                                    // 33792 B epilogue (m-half)
    } sm;
    // T1 swizzle: 512 wgs, 64/XCD; 2 m-blocks of one (b,n0) B-panel consecutive on one XCD
    const int lin = blockIdx.x + ((blockIdx.y + blockIdx.z * 2) << 3);
    const int xcd = lin & 7, idx = lin >> 3;
    const int gwk = xcd * 64 + idx;
    const int mt = gwk & 1, panel = gwk >> 1;
    const int b = panel >> 3;
    const int n0 = (panel & 7) * 128, m0 = mt * 128;
    const int t = threadIdx.x;
    const int wave = t >> 6, lane = t & 63, quad = lane >> 4, l16 = lane & 15;
    const int wm = (wave & 1) * 64, wn = (wave >> 1) * 64;
    const __bf16* arow = wbf_out + (size_t)m0 * 256;
    const __bf16* brow = aoT + ((size_t)b * 1024 + n0) * 256;
    auto As = sm.g.A;
    auto Bs = sm.g.B;

    GEMM64G_BODY(arow, brow)

    for (int h = 0; h < 2; h++) {
        if ((wave & 1) == h) {
            #pragma unroll
            for (int im = 0; im < 4; im++)
                #pragma unroll
                for (int in = 0; in < 4; in++)
                    #pragma unroll
                    for (int r = 0; r < 4; r++)
                        sm.cf[im * 16 + quad * 4 + r][wn + in * 16 + l16] = acc[im][in][r];
        }
        __syncthreads();
        {
            const int rloc = t >> 2, cq = (t & 3) * 4;
            const int o = m0 + h * 64 + rloc;
            const float bo = bias[o];
            const float* rrow = &resid[((size_t)b * 256 + o) * 1024 + n0];
            float* orow = &Out[((size_t)b * 256 + o) * 1024 + n0];
            #pragma unroll
            for (int u = 0; u < 8; u++) {
                int col = cq + u * 16;
                f32x4 cv = *(const f32x4*)&sm.cf[rloc][col];
                float4 rv = *(const float4*)&rrow[col];
                float4 ov;
                ov.x = cv[0] + bo + rv.x;
                ov.y = cv[1] + bo + rv.y;
                ov.z = cv[2] + bo + rv.z;
                ov.w = cv[3] + bo + rv.w;
                *(float4*)&orow[col] = ov;
            }
        }
        __syncthreads();
    }
}

extern "C" void kernel_launch(void* const* d_in, const int* in_sizes, int n_in,
                              void* d_out, int out_size, void* d_ws, size_t ws_size,
                              hipStream_t stream) {
    const float* x    = (const float*)d_in[0];
    const float* gw   = (const float*)d_in[1];
    const float* gb   = (const float*)d_in[2];
    const float* wqkv = (const float*)d_in[3];
    const float* bqkv = (const float*)d_in[4];
    const float* wout = (const float*)d_in[5];
    const float* bout = (const float*)d_in[6];
    float* out = (float*)d_out;

    const size_t T16 = (size_t)32 * 1024 * 256;
    __bf16* xnT  = (__bf16*)d_ws;        // [b][s][c]
    __bf16* qtr  = xnT + T16;            // [b][s][c]
    __bf16* ktr  = qtr + T16;            // [b][t][c]
    __bf16* vbuf = ktr + T16;            // [b][c][t]
    __bf16* aoT  = vbuf + T16;           // [b][s][c]
    __bf16* wbf  = aoT + T16;            // wqkv_bf16 (196608) | wout_bf16 (65536)
    float* gstats = (float*)(wbf + 262144);  // [256 groups][8 parts][2]

    gn_stats<<<dim3(2048), 256, 0, stream>>>(x, gstats, wqkv, wout, wbf);
    gn_apply<<<dim3(2048), 512, 0, stream>>>(x, gstats, gw, gb, xnT);
    qkv_gemm<<<dim3(8, 6, 32), 256, 0, stream>>>(wbf, bqkv, xnT, qtr, ktr, vbuf);
    attn_kernel<<<dim3(32, 8), 512, 0, stream>>>(qtr, ktr, vbuf, aoT);
    proj_gemm<<<dim3(8, 2, 32), 256, 0, stream>>>(wbf + 196608, bout, aoT, x, out);
}

// Round 7
// 185.227 us; speedup vs baseline: 1.0577x; 1.0065x over previous
//
#include <hip/hip_runtime.h>
#include <hip/hip_bf16.h>

// AttentionBlock: GroupNorm(8) -> QKV 1x1 -> softmax attention (hw=1024, c=256) -> proj + residual
// B=32, C=256, H=W=32. Inputs fp32, OUTPUT fp32. Internals bf16 MFMA, fp32 accum.
// R16:
//  - qkv/proj GEMM body: 2-phase counted-vmcnt pipeline (T3/T4 minimum recipe). Double-buffered
//    LDS (64KB), STAGE(k+1) issued before compute(k), raw s_barrier + s_waitcnt vmcnt(8)
//    (never 0 in-loop) so next tile's loads fly under MFMA. lgkmcnt(0) drain before trailing
//    barrier protects cross-wave LDS read-vs-gload-write. 2 blocks/CU (was 4).
//  - gn_apply: LDS layout flipped to [c][s] — kills the 16-way scalar-write bank conflict
//    (8-row stepping x any 16B-multiple stride aliases mod 128). Writes now b128 ~2-way;
//    transpose moved to read side (8 scalar b16, ~2-way spread).
//  - attn: unchanged (55.2us anchor). gn_stats unchanged.
// ws: xnT 16MB | qtr 16MB | ktr 16MB | v 16MB | aoT 16MB | wbf 512KB | gstats 16KB.

typedef __bf16 bf16x8 __attribute__((ext_vector_type(8)));
typedef __bf16 bf16x4 __attribute__((ext_vector_type(4)));
typedef float f32x4 __attribute__((ext_vector_type(4)));
typedef float f32x16 __attribute__((ext_vector_type(16)));

#define MFMA16(a, b, c) __builtin_amdgcn_mfma_f32_16x16x32_bf16(a, b, c, 0, 0, 0)
#define MFMA32(a, b, c) __builtin_amdgcn_mfma_f32_32x32x16_bf16(a, b, c, 0, 0, 0)

#define GLD16(gsrc_, ldst_)                                                                  \
    __builtin_amdgcn_global_load_lds((const __attribute__((address_space(1))) void*)(gsrc_), \
                                     (__attribute__((address_space(3))) void*)(ldst_), 16, 0, 0)

// ---------------- K0: GN partial stats (2048 blocks) + fused weight convert ----------------
__global__ __launch_bounds__(256) void gn_stats(const float* __restrict__ x,
                                                float* __restrict__ stats,
                                                const float* __restrict__ wqkv,
                                                const float* __restrict__ wout,
                                                __bf16* __restrict__ wbf) {
    const int bid = blockIdx.x, t = threadIdx.x;
    // fused wconv on first 128 blocks: 128*256*8 = 262144 (wqkv 196608 | wout 65536)
    if (bid < 128) {
        int idx = (bid * 256 + t) * 8;
        const float* src = (idx < 196608) ? (wqkv + idx) : (wout + (idx - 196608));
        float4 v0 = *(const float4*)src;
        float4 v1 = *(const float4*)(src + 4);
        bf16x8 o;
        o[0] = (__bf16)v0.x; o[1] = (__bf16)v0.y; o[2] = (__bf16)v0.z; o[3] = (__bf16)v0.w;
        o[4] = (__bf16)v1.x; o[5] = (__bf16)v1.y; o[6] = (__bf16)v1.z; o[7] = (__bf16)v1.w;
        *(bf16x8*)&wbf[idx] = o;
    }
    // partial sums: group bg (0..255), part (0..7), 4096 floats per block
    const int bg = bid >> 3, part = bid & 7;
    const float* xp = x + (size_t)bg * 32768 + part * 4096;
    float s = 0.f, s2 = 0.f;
    #pragma unroll
    for (int i = 0; i < 4; i++) {
        float4 v = *(const float4*)(xp + (i * 256 + t) * 4);
        s  += v.x + v.y + v.z + v.w;
        s2 += v.x*v.x + v.y*v.y + v.z*v.z + v.w*v.w;
    }
    #pragma unroll
    for (int o = 32; o > 0; o >>= 1) { s += __shfl_down(s, o, 64); s2 += __shfl_down(s2, o, 64); }
    __shared__ float red[8];
    const int wv = t >> 6;
    if ((t & 63) == 0) { red[wv * 2] = s; red[wv * 2 + 1] = s2; }
    __syncthreads();
    if (t == 0) {
        float ts  = red[0] + red[2] + red[4] + red[6];
        float ts2 = red[1] + red[3] + red[5] + red[7];
        stats[bg * 16 + part * 2]     = ts;
        stats[bg * 16 + part * 2 + 1] = ts2;
    }
}

// ---------------- K1: GN apply, fp32 [b][c][s] -> bf16 xnT [b][s][c], 2048 blocks ----------------
__global__ __launch_bounds__(512) void gn_apply(const float* __restrict__ x,
                                                const float* __restrict__ stats,
                                                const float* __restrict__ gw,
                                                const float* __restrict__ gb,
                                                __bf16* __restrict__ xnT) {
    const int bid = blockIdx.x;          // 0..2047
    const int bg = bid >> 3, part = bid & 7;
    const int b = bg >> 3, g = bg & 7;
    const int t = threadIdx.x;
    float ts = 0.f, ts2 = 0.f;
    #pragma unroll
    for (int p = 0; p < 8; p++) { ts += stats[bg * 16 + p * 2]; ts2 += stats[bg * 16 + p * 2 + 1]; }
    const float mean = ts / 32768.f;
    const float inv = rsqrtf(ts2 / 32768.f - mean * mean + 1e-5f);
    __shared__ __bf16 Lds[32][136];      // [c][s] + 8 pad: b128 writes ~2-way, scalar reads ~2-way
    const int c = t >> 4, ss = (t & 15) * 8;
    const float ga = gw[g * 32 + c], be = gb[g * 32 + c];
    const float* xp = x + (((size_t)b * 256 + g * 32 + c) * 1024) + part * 128 + ss;
    float4 v0 = *(const float4*)xp;
    float4 v1 = *(const float4*)(xp + 4);
    float vv[8] = {v0.x, v0.y, v0.z, v0.w, v1.x, v1.y, v1.z, v1.w};
    bf16x8 wv;
    #pragma unroll
    for (int i = 0; i < 8; i++) wv[i] = (__bf16)((vv[i] - mean) * inv * ga + be);
    *(bf16x8*)&Lds[c][ss] = wv;
    __syncthreads();
    const int row = t >> 2, cb = (t & 3) * 8;
    bf16x8 ov;
    #pragma unroll
    for (int j = 0; j < 8; j++) ov[j] = Lds[cb + j][row];
    *(bf16x8*)&xnT[((size_t)b * 1024 + part * 128 + row) * 256 + g * 32 + cb] = ov;
}

// ---------------- 128x128 GEMM body: 2-phase counted-vmcnt pipeline, gload_lds + XOR swizzle ----------------
// K=256 in 4 steps of 64. Double-buffered As/Bs[2][128][64]. Per stage: 8 gload_lds/wave.
// vmcnt(8) = prior stage's loads done while current stage's 8 stay in flight (T4).
// lgkmcnt(0) before trailing barrier: this wave's ds_reads complete before any wave's
// next-next stage can overwrite the buffer it was reading.
#define GEMM64P_BODY(ArowBase_, BrowBase_)                                              \
    f32x4 acc[4][4] = {};                                                               \
    {                                                                                   \
        _Pragma("unroll")                                                               \
        for (int i = 0; i < 4; i++) {                                                   \
            const int ch = wave * 4 + i;                                                \
            const int r = ch * 8 + (lane >> 3);                                         \
            const int sw = ((lane & 7) ^ (r & 7)) * 8;                                  \
            GLD16((ArowBase_) + (size_t)r * 256 + sw, (char*)&As[0][0][0] + ch * 1024); \
            GLD16((BrowBase_) + (size_t)r * 256 + sw, (char*)&Bs[0][0][0] + ch * 1024); \
        }                                                                               \
    }                                                                                   \
    _Pragma("unroll")                                                                   \
    for (int kk = 0; kk < 4; kk++) {                                                    \
        if (kk < 3) {                                                                   \
            _Pragma("unroll")                                                           \
            for (int i = 0; i < 4; i++) {                                               \
                const int ch = wave * 4 + i;                                            \
                const int r = ch * 8 + (lane >> 3);                                     \
                const int sw = ((lane & 7) ^ (r & 7)) * 8;                              \
                GLD16((ArowBase_) + (size_t)r * 256 + (kk + 1) * 64 + sw,               \
                      (char*)&As[(kk + 1) & 1][0][0] + ch * 1024);                      \
                GLD16((BrowBase_) + (size_t)r * 256 + (kk + 1) * 64 + sw,               \
                      (char*)&Bs[(kk + 1) & 1][0][0] + ch * 1024);                      \
            }                                                                           \
            asm volatile("s_waitcnt vmcnt(8)" ::: "memory");                            \
        } else {                                                                        \
            asm volatile("s_waitcnt vmcnt(0)" ::: "memory");                            \
        }                                                                               \
        asm volatile("s_barrier" ::: "memory");                                         \
        _Pragma("unroll")                                                               \
        for (int kh = 0; kh < 2; kh++) {                                                \
            bf16x8 af[4], bfv[4];                                                       \
            _Pragma("unroll")                                                           \
            for (int im = 0; im < 4; im++) {                                            \
                const int row = wm + im * 16 + l16;                                     \
                af[im] = *(const bf16x8*)&As[kk & 1][row][(((kh * 4 + quad) ^ (row & 7)) * 8)]; \
            }                                                                           \
            _Pragma("unroll")                                                           \
            for (int in = 0; in < 4; in++) {                                            \
                const int row = wn + in * 16 + l16;                                     \
                bfv[in] = *(const bf16x8*)&Bs[kk & 1][row][(((kh * 4 + quad) ^ (row & 7)) * 8)]; \
            }                                                                           \
            _Pragma("unroll")                                                           \
            for (int im = 0; im < 4; im++)                                              \
                _Pragma("unroll")                                                       \
                for (int in = 0; in < 4; in++)                                          \
                    acc[im][in] = MFMA16(af[im], bfv[in], acc[im][in]);                 \
        }                                                                               \
        asm volatile("s_waitcnt lgkmcnt(0)" ::: "memory");                              \
        asm volatile("s_barrier" ::: "memory");                                        \
    }

// ---------------- K2: QKV GEMM, 128x128 tiles, XCD-chunked swizzle ----------------
__global__ __launch_bounds__(256) void qkv_gemm(const __bf16* __restrict__ wbf,
                                                const float* __restrict__ bias,
                                                const __bf16* __restrict__ xnT,
                                                __bf16* __restrict__ qtr,
                                                __bf16* __restrict__ ktr,
                                                __bf16* __restrict__ vbuf) {
    __shared__ union {
        struct { __bf16 A[2][128][64]; __bf16 B[2][128][64]; } g;  // 65536 B dbuf main loop
        __bf16 ct[128][136];                                       // 34816 B epilogue
    } sm;
    // T1 swizzle: 1536 wgs, 192/XCD; 6 m-blocks of one (b,n0) B-panel consecutive on one XCD
    const int lin = blockIdx.x + ((blockIdx.y + blockIdx.z * 6) << 3);
    const int xcd = lin & 7, idx = lin >> 3;
    const int gwk = xcd * 192 + idx;
    const int mt = gwk % 6, panel = gwk / 6;
    const int b = panel >> 3;
    const int n0 = (panel & 7) * 128, m0 = mt * 128;
    const int t = threadIdx.x;
    const int wave = t >> 6, lane = t & 63, quad = lane >> 4, l16 = lane & 15;
    const int wm = (wave & 1) * 64, wn = (wave >> 1) * 64;
    const __bf16* arow = wbf + (size_t)m0 * 256;
    const __bf16* brow = xnT + ((size_t)b * 1024 + n0) * 256;
    auto As = sm.g.A;
    auto Bs = sm.g.B;

    GEMM64P_BODY(arow, brow)

    if (m0 < 512) {
        // q/k path: transpose C-tile into LDS [s][c], then coalesced bf16x8 stores.
        #pragma unroll
        for (int im = 0; im < 4; im++) {
            #pragma unroll
            for (int in = 0; in < 4; in++) {
                int ob = m0 + wm + im * 16 + quad * 4;
                bf16x4 ov;
                #pragma unroll
                for (int r = 0; r < 4; r++) ov[r] = (__bf16)(acc[im][in][r] + bias[ob + r]);
                *(bf16x4*)&sm.ct[wn + in * 16 + l16][wm + im * 16 + quad * 4] = ov;
            }
        }
        __syncthreads();
        {
            const int rbase = t >> 2, cf = t & 3;
            #pragma unroll
            for (int rr = 0; rr < 2; rr++) {
                int row = rbase + rr * 64;
                int sg = n0 + row;
                __bf16* dst = (m0 < 256) ? &qtr[((size_t)b * 1024 + sg) * 256 + m0]
                                         : &ktr[((size_t)b * 1024 + sg) * 256 + (m0 - 256)];
                #pragma unroll
                for (int u = 0; u < 4; u++) {
                    int colb = cf * 8 + u * 32;
                    *(bf16x8*)&dst[colb] = *(const bf16x8*)&sm.ct[row][colb];
                }
            }
        }
    } else {
        // v path: stage C-tile into LDS as [c][t], then fully-coalesced b128 stores to vbuf [b][c][t].
        #pragma unroll
        for (int im = 0; im < 4; im++) {
            #pragma unroll
            for (int in = 0; in < 4; in++) {
                int cl = wm + im * 16 + quad * 4;
                int tl = wn + in * 16 + l16;
                #pragma unroll
                for (int r = 0; r < 4; r++)
                    sm.ct[cl + r][tl] = (__bf16)(acc[im][in][r] + bias[m0 + cl + r]);
            }
        }
        __syncthreads();
        {
            const int row = t >> 1, tc = (t & 1) * 64;   // c_local row, t-chunk base
            const int cglob = m0 - 512 + row;
            __bf16* dst = &vbuf[((size_t)b * 256 + cglob) * 1024 + n0 + tc];
            #pragma unroll
            for (int u = 0; u < 8; u++)
                *(bf16x8*)&dst[u * 8] = *(const bf16x8*)&sm.ct[row][tc + u * 8];
        }
    }
}

// ---------------- K3: fused flash attention (R12 structure: swapped QK^T, permuted-V, T14 prefetch) ----------------
__global__ __launch_bounds__(512, 2) void attn_kernel(const __bf16* __restrict__ qtr,
                                                      const __bf16* __restrict__ ktr,
                                                      const __bf16* __restrict__ vbuf,
                                                      __bf16* __restrict__ aoT) {
    __shared__ __bf16 Kt[2][32][260];     // [t-half][t_local][c]
    __shared__ __bf16 Vs[2][256][36];     // [t-half][c][slot]  (slot = permuted t within 16-chunks)
    __shared__ bf16x8 Pl[4][2][2][64];    // [pair][th][chunk][lane] P-fragments for partner wave
    __shared__ float Lred[4][2][32];      // [pair][th][s_local]
    const int b = blockIdx.x;
    const int tid = threadIdx.x;
    const int wave = tid >> 6, lane = tid & 63, half = lane >> 5, l31 = lane & 31;
    const int pair = wave & 3, th = wave >> 2;
    const int s0 = blockIdx.y * 128 + pair * 32;
    const float kscale = 0.09016844f;   // (1/16) * log2(e); p = exp2(s * kscale)

    // Q fragments (B-operand of swapped QK: lane = s-col, elems = c)
    bf16x8 aq[16];
    #pragma unroll
    for (int ks = 0; ks < 16; ks++)
        aq[ks] = *(const bf16x8*)&qtr[((size_t)b * 1024 + s0 + l31) * 256 + ks * 16 + half * 8];

    const int k_row = tid >> 3;
    const int k_cb  = (tid & 7) * 8;
    const int v_c   = tid >> 1;
    const int v_th  = tid & 1;
    const size_t kbase = (size_t)b * 1024 * 256;
    const size_t vbase = (size_t)b * 256 * 1024;

    float l_acc = 0.f;
    f32x16 o_acc[4] = {};

    // prologue: prefetch tile 0 into registers
    bf16x8 kpre[4], vpre[4];
    #pragma unroll
    for (int u = 0; u < 4; u++) {
        kpre[u] = *(const bf16x8*)&ktr[kbase + (size_t)k_row * 256 + k_cb + u * 64];
        vpre[u] = *(const bf16x8*)&vbuf[vbase + (size_t)v_c * 1024 + v_th * 32 + u * 8];
    }

    for (int it = 0; it < 16; it++) {
        // stage K (linear) and V (slot-permuted: within each 16-t chunk, t-groups [0-3,4-7,8-11,12-15]
        // land at slots [0-3,8-11,4-7,12-15] so p-register order matches MFMA k-slots)
        #pragma unroll
        for (int u = 0; u < 4; u++)
            *(bf16x8*)&Kt[k_row >> 5][k_row & 31][k_cb + u * 64] = kpre[u];
        #pragma unroll
        for (int u = 0; u < 4; u++) {
            const bf16x4* hv = (const bf16x4*)&vpre[u];
            const int sbase = (u >> 1) * 16 + (u & 1) * 4;   // 0,4,16,20
            *(bf16x4*)&Vs[v_th][v_c][sbase]     = hv[0];
            *(bf16x4*)&Vs[v_th][v_c][sbase + 8] = hv[1];
        }
        __syncthreads();
        // T14: issue next tile's global loads NOW — they fly under QK + softmax
        if (it < 15) {
            const int t1 = (it + 1) * 64;
            #pragma unroll
            for (int u = 0; u < 4; u++) {
                kpre[u] = *(const bf16x8*)&ktr[kbase + (size_t)(t1 + k_row) * 256 + k_cb + u * 64];
                vpre[u] = *(const bf16x8*)&vbuf[vbase + (size_t)v_c * 1024 + t1 + v_th * 32 + u * 8];
            }
        }

        // swapped QK^T: A = K (lane = t-row), B = Q (lane = s-col) -> C: regs = t, lane = s
        f32x16 sc_a = {}, sc_b = {};
        __builtin_amdgcn_s_setprio(1);
        #pragma unroll
        for (int ks = 0; ks < 8; ks++) {
            bf16x8 bk0 = *(const bf16x8*)&Kt[th][l31][ks * 16 + half * 8];
            bf16x8 bk1 = *(const bf16x8*)&Kt[th][l31][(ks + 8) * 16 + half * 8];
            sc_a = MFMA32(bk0, aq[ks], sc_a);
            sc_b = MFMA32(bk1, aq[ks + 8], sc_b);
        }
        __builtin_amdgcn_s_setprio(0);

        // softmax partial + P fragments (lane = s, regs = t -> direct PV A-operand)
        bf16x8 pf0, pf1;
        #pragma unroll
        for (int r = 0; r < 8; r++) {
            float p = exp2f((sc_a[r] + sc_b[r]) * kscale);
            l_acc += p;
            pf0[r] = (__bf16)p;
        }
        #pragma unroll
        for (int r = 8; r < 16; r++) {
            float p = exp2f((sc_a[r] + sc_b[r]) * kscale);
            l_acc += p;
            pf1[r - 8] = (__bf16)p;
        }
        Pl[pair][th][0][lane] = pf0;
        Pl[pair][th][1][lane] = pf1;
        __syncthreads();
        bf16x8 pp0 = Pl[pair][1 - th][0][lane];
        bf16x8 pp1 = Pl[pair][1 - th][1][lane];

        bf16x8 ap[4];
        if (th == 0) { ap[0] = pf0; ap[1] = pf1; ap[2] = pp0; ap[3] = pp1; }
        else         { ap[0] = pp0; ap[1] = pp1; ap[2] = pf0; ap[3] = pf1; }

        __builtin_amdgcn_s_setprio(1);
        #pragma unroll
        for (int n = 0; n < 4; n++) {
            int c = th * 128 + n * 32 + l31;
            #pragma unroll
            for (int kc = 0; kc < 4; kc++) {
                bf16x8 bv = *(const bf16x8*)&Vs[kc >> 1][c][(kc & 1) * 16 + half * 8];
                o_acc[n] = MFMA32(ap[kc], bv, o_acc[n]);
            }
        }
        __builtin_amdgcn_s_setprio(0);
        __syncthreads();
    }

    // l reduction: combine lane-halves (same s), then th-pairs via LDS
    l_acc += __shfl_xor(l_acc, 32, 64);
    if (lane < 32) Lred[pair][th][l31] = l_acc;
    __syncthreads();
    #pragma unroll
    for (int r = 0; r < 16; r++) {
        int row = (r & 3) + 8 * (r >> 2) + 4 * half;
        float rinv = 1.0f / (Lred[pair][0][row] + Lred[pair][1][row]);
        #pragma unroll
        for (int n = 0; n < 4; n++) {
            int c = th * 128 + n * 32 + l31;
            aoT[((size_t)b * 1024 + s0 + row) * 256 + c] = (__bf16)(o_acc[n][r] * rinv);
        }
    }
}

// ---------------- K4: proj GEMM, 128x128 tiles, XCD-chunked swizzle ----------------
__global__ __launch_bounds__(256) void proj_gemm(const __bf16* __restrict__ wbf_out,
                                                 const float* __restrict__ bias,
                                                 const __bf16* __restrict__ aoT,
                                                 const float* __restrict__ resid,
                                                 float* __restrict__ Out) {
    __shared__ union {
        struct { __bf16 A[2][128][64]; __bf16 B[2][128][64]; } g;  // 65536 B dbuf main loop
        float cf[64][132];                                         // 33792 B epilogue (m-half)
    } sm;
    // T1 swizzle: 512 wgs, 64/XCD; 2 m-blocks of one (b,n0) B-panel consecutive on one XCD
    const int lin = blockIdx.x + ((blockIdx.y + blockIdx.z * 2) << 3);
    const int xcd = lin & 7, idx = lin >> 3;
    const int gwk = xcd * 64 + idx;
    const int mt = gwk & 1, panel = gwk >> 1;
    const int b = panel >> 3;
    const int n0 = (panel & 7) * 128, m0 = mt * 128;
    const int t = threadIdx.x;
    const int wave = t >> 6, lane = t & 63, quad = lane >> 4, l16 = lane & 15;
    const int wm = (wave & 1) * 64, wn = (wave >> 1) * 64;
    const __bf16* arow = wbf_out + (size_t)m0 * 256;
    const __bf16* brow = aoT + ((size_t)b * 1024 + n0) * 256;
    auto As = sm.g.A;
    auto Bs = sm.g.B;

    GEMM64P_BODY(arow, brow)

    for (int h = 0; h < 2; h++) {
        if ((wave & 1) == h) {
            #pragma unroll
            for (int im = 0; im < 4; im++)
                #pragma unroll
                for (int in = 0; in < 4; in++)
                    #pragma unroll
                    for (int r = 0; r < 4; r++)
                        sm.cf[im * 16 + quad * 4 + r][wn + in * 16 + l16] = acc[im][in][r];
        }
        __syncthreads();
        {
            const int rloc = t >> 2, cq = (t & 3) * 4;
            const int o = m0 + h * 64 + rloc;
            const float bo = bias[o];
            const float* rrow = &resid[((size_t)b * 256 + o) * 1024 + n0];
            float* orow = &Out[((size_t)b * 256 + o) * 1024 + n0];
            #pragma unroll
            for (int u = 0; u < 8; u++) {
                int col = cq + u * 16;
                f32x4 cv = *(const f32x4*)&sm.cf[rloc][col];
                float4 rv = *(const float4*)&rrow[col];
                float4 ov;
                ov.x = cv[0] + bo + rv.x;
                ov.y = cv[1] + bo + rv.y;
                ov.z = cv[2] + bo + rv.z;
                ov.w = cv[3] + bo + rv.w;
                *(float4*)&orow[col] = ov;
            }
        }
        __syncthreads();
    }
}

extern "C" void kernel_launch(void* const* d_in, const int* in_sizes, int n_in,
                              void* d_out, int out_size, void* d_ws, size_t ws_size,
                              hipStream_t stream) {
    const float* x    = (const float*)d_in[0];
    const float* gw   = (const float*)d_in[1];
    const float* gb   = (const float*)d_in[2];
    const float* wqkv = (const float*)d_in[3];
    const float* bqkv = (const float*)d_in[4];
    const float* wout = (const float*)d_in[5];
    const float* bout = (const float*)d_in[6];
    float* out = (float*)d_out;

    const size_t T16 = (size_t)32 * 1024 * 256;
    __bf16* xnT  = (__bf16*)d_ws;        // [b][s][c]
    __bf16* qtr  = xnT + T16;            // [b][s][c]
    __bf16* ktr  = qtr + T16;            // [b][t][c]
    __bf16* vbuf = ktr + T16;            // [b][c][t]
    __bf16* aoT  = vbuf + T16;           // [b][s][c]
    __bf16* wbf  = aoT + T16;            // wqkv_bf16 (196608) | wout_bf16 (65536)
    float* gstats = (float*)(wbf + 262144);  // [256 groups][8 parts][2]

    gn_stats<<<dim3(2048), 256, 0, stream>>>(x, gstats, wqkv, wout, wbf);
    gn_apply<<<dim3(2048), 512, 0, stream>>>(x, gstats, gw, gb, xnT);
    qkv_gemm<<<dim3(8, 6, 32), 256, 0, stream>>>(wbf, bqkv, xnT, qtr, ktr, vbuf);
    attn_kernel<<<dim3(32, 8), 512, 0, stream>>>(qtr, ktr, vbuf, aoT);
    proj_gemm<<<dim3(8, 2, 32), 256, 0, stream>>>(wbf + 196608, bout, aoT, x, out);
}